// Round 9
// baseline (44873.920 us; speedup 1.0000x reference)
//
#include <hip/hip_runtime.h>
#include <hip/hip_bf16.h>
#include <cstdint>
#include <cstddef>

// ---------------------------------------------------------------------------
// FlumenHead: encoder MLP (32->512->512->1024) + 2048-step LSTM (D=9, F=1024)
// v8: 32 WGs x 512 (v5 sync, proven cheap) + fragment-linear conflict-free
// LDS (v7b-proven) + 2 M-tiles/wave with A pinned in 256 AGPRs via inline-asm
// MFMA ("a" operand class) -> per-CU LDS read halved (each B-frag feeds 2
// MFMAs). s_nop block covers MFMA->VALU hazard invisible to the compiler.
// ---------------------------------------------------------------------------

typedef __bf16 bf16x8_t __attribute__((ext_vector_type(8)));
typedef float f32x4_t __attribute__((ext_vector_type(4)));
typedef int   i32x4_t __attribute__((ext_vector_type(4)));
typedef unsigned long long u64_t;
typedef unsigned long long u64x2_t __attribute__((ext_vector_type(2)));
typedef unsigned short u16x4_t __attribute__((ext_vector_type(4)));

// workspace layout (bytes); total ~18.6 MB
#define WS_TAGS    0          // int  tags[2048][32][4] (16B per (t,w))   1 MB
#define WS_HBUF    1048576    // u16  hbuf[2][128 blk][64 ln][8] bf16   256 KB
#define WS_WSHUF   1310720    // u16  Wshuf[256 mt][32 kt][64 ln][8]      8 MB
#define WS_WAUG    9699328    // u16  WaugI[256 mt][64 ln][8]           256 KB
#define WS_XHAT    9961472    // u16  Xhat[2048 t][64 b][32] bf16         8 MB
#define WS_H1      18350080   // f32  h1[64][512]                       128 KB
#define WS_H2      18481152   // f32  h2[64][512]                       128 KB

__device__ __forceinline__ unsigned short f2bf(float f) {
  unsigned int u = __float_as_uint(f);
  u = (u + 0x7fffu + ((u >> 16) & 1u)) >> 16;   // RNE
  return (unsigned short)u;
}
__device__ __forceinline__ float sigm(float x) { return 1.f / (1.f + __expf(-x)); }
__device__ __forceinline__ float tanh_f(float x) {
  float e = __expf(-2.f * fabsf(x));
  float r = (1.f - e) / (1.f + e);
  return copysignf(r, x);
}

// ---------------------------- encoder ----------------------------

__global__ void flumen_enc1(const float* __restrict__ x, const float* __restrict__ W,
                            const float* __restrict__ b, float* __restrict__ h1) {
  const int bb = blockIdx.x;   // batch 0..63
  const int o  = threadIdx.x;  // 0..511
  const f32x4_t* xr = (const f32x4_t*)(x + bb * 32);
  const f32x4_t* wr = (const f32x4_t*)(W + o * 32);
  float acc = b[o];
#pragma unroll
  for (int q = 0; q < 8; ++q) {
    f32x4_t xv = xr[q], wv = wr[q];
    acc += xv[0] * wv[0] + xv[1] * wv[1] + xv[2] * wv[2] + xv[3] * wv[3];
  }
  h1[bb * 512 + o] = fmaxf(acc, 0.f);
}

__global__ void flumen_enc2(const float* __restrict__ in, const float* __restrict__ W,
                            const float* __restrict__ bv, float* __restrict__ outb) {
  __shared__ float s[64 * 256];
  const int tid = threadIdx.x;
  const int ol = tid & 63, bg = tid >> 6;
  const int o = blockIdx.x * 64 + ol;
  float bias = bv[o];
  float acc[8];
#pragma unroll
  for (int q = 0; q < 8; ++q) acc[q] = bias;
  for (int p = 0; p < 2; ++p) {
    __syncthreads();
    for (int i = tid; i < 4096; i += 512) {
      int flat = i * 4;
      int bb = flat >> 8, kk = flat & 255;
      *(f32x4_t*)(s + flat) = *(const f32x4_t*)(in + bb * 512 + p * 256 + kk);
    }
    __syncthreads();
    for (int kk = 0; kk < 256; kk += 4) {
      f32x4_t wv = *(const f32x4_t*)(W + o * 512 + p * 256 + kk);
#pragma unroll
      for (int j = 0; j < 4; ++j) {
        float wj = wv[j];
#pragma unroll
        for (int q = 0; q < 8; ++q)
          acc[q] += wj * s[(bg * 8 + q) * 256 + kk + j];
      }
    }
  }
#pragma unroll
  for (int q = 0; q < 8; ++q)
    outb[(bg * 8 + q) * 512 + o] = fmaxf(acc[q], 0.f);
}

__global__ void flumen_enc3(const float* __restrict__ in, const float* __restrict__ W,
                            const float* __restrict__ bv, float* __restrict__ dout,
                            unsigned short* __restrict__ hbuf) {
  __shared__ float s[64 * 256];
  const int tid = threadIdx.x;
  const int ol = tid & 63, bg = tid >> 6;
  const int o = blockIdx.x * 64 + ol;   // 0..1023
  float bias = bv[o];
  float acc[8];
#pragma unroll
  for (int q = 0; q < 8; ++q) acc[q] = bias;
  for (int p = 0; p < 2; ++p) {
    __syncthreads();
    for (int i = tid; i < 4096; i += 512) {
      int flat = i * 4;
      int bb = flat >> 8, kk = flat & 255;
      *(f32x4_t*)(s + flat) = *(const f32x4_t*)(in + bb * 512 + p * 256 + kk);
    }
    __syncthreads();
    for (int kk = 0; kk < 256; kk += 4) {
      f32x4_t wv = *(const f32x4_t*)(W + o * 512 + p * 256 + kk);
#pragma unroll
      for (int j = 0; j < 4; ++j) {
        float wj = wv[j];
#pragma unroll
        for (int q = 0; q < 8; ++q)
          acc[q] += wj * s[(bg * 8 + q) * 256 + kk + j];
      }
    }
  }
  float* out_hseq = dout + 65536;
#pragma unroll
  for (int q = 0; q < 8; ++q) {
    int bb = bg * 8 + q;
    float v = acc[q];
    out_hseq[(size_t)bb * 2097152 + o] = v;   // h_seq[b][0][o]
    // fragment-linear hbuf[0]: block = (b>>4)*32 + (o>>5),
    // lane = ((o>>3)&3)*16 + (b&15), e = o&7
    int blk  = (bb >> 4) * 32 + (o >> 5);
    int lane = ((o >> 3) & 3) * 16 + (bb & 15);
    hbuf[blk * 512 + lane * 8 + (o & 7)] = f2bf(v);
  }
}

// ---------------------------- precompute ----------------------------

// Gate-interleaved A fragments: Wshuf[mt][kt][lane][8],
// A row r = lane&15 -> gate g = r&3, feature f = mt*4 + (r>>2);
// k = kt*32 + (lane>>4)*8 + e; src = w_hh[(g*1024+f)*1024 + k].
__global__ void flumen_wshuf(const float* __restrict__ src, unsigned short* __restrict__ dst) {
  int idx = blockIdx.x * 512 + threadIdx.x;      // 0..524287
  int lane = idx & 63, kt = (idx >> 6) & 31, mt = idx >> 11;
  int r = lane & 15;
  int g = r & 3, f = mt * 4 + (r >> 2);
  int k0 = kt * 32 + (lane >> 4) * 8;
  const float* sp = src + (size_t)(g * 1024 + f) * 1024 + k0;
  f32x4_t v0 = *(const f32x4_t*)(sp);
  f32x4_t v1 = *(const f32x4_t*)(sp + 4);
  u16x4_t o0, o1;
#pragma unroll
  for (int j = 0; j < 4; ++j) { o0[j] = f2bf(v0[j]); o1[j] = f2bf(v1[j]); }
  u16x4_t* dp = (u16x4_t*)(dst + (size_t)idx * 8);
  dp[0] = o0; dp[1] = o1;
}

// Gate-interleaved augmented fragments: WaugI[mt][lane][8], K=32:
// k<9 -> w_ih[(g*1024+f)*9+k], k==9 -> bias[g*1024+f], else 0.
__global__ void flumen_waugi(const float* __restrict__ wih, const float* __restrict__ bias,
                             unsigned short* __restrict__ dst) {
  int idx = blockIdx.x * 512 + threadIdx.x;      // 0..16383
  int lane = idx & 63, mt = idx >> 6;
  int r = lane & 15;
  int g = r & 3, f = mt * 4 + (r >> 2);
  int k0 = (lane >> 4) * 8;
  unsigned short o[8];
#pragma unroll
  for (int j = 0; j < 8; ++j) {
    int k = k0 + j;
    float v = (k < 9) ? wih[(size_t)(g * 1024 + f) * 9 + k]
                      : (k == 9 ? bias[g * 1024 + f] : 0.f);
    o[j] = f2bf(v);
  }
  u16x4_t* dp = (u16x4_t*)(dst + (size_t)idx * 8);
  dp[0] = *(u16x4_t*)&o[0];
  dp[1] = *(u16x4_t*)&o[4];
}

// Xhat[t][b][0..8]=x[b][t][:], [9]=1.0, rest 0. grid=2048.
__global__ void flumen_convx(const float* __restrict__ xin, unsigned short* __restrict__ dst) {
  int i = (blockIdx.x * 512 + threadIdx.x) * 4;   // elem index, 4 at a time
  int b = i >> 16, t = (i >> 5) & 2047, c0 = i & 31;
  u16x4_t o;
#pragma unroll
  for (int j = 0; j < 4; ++j) {
    int cc = c0 + j;
    float v = (cc < 9) ? xin[((size_t)b * 2048 + t) * 9 + cc] : (cc == 9 ? 1.f : 0.f);
    o[j] = f2bf(v);
  }
  *(u16x4_t*)(dst + ((size_t)t * 64 + b) * 32 + c0) = o;
}

// ---------------------------- persistent LSTM ----------------------------
// 32 WGs x 512 thr, 1 WG/CU (137 KB LDS). WG w owns features [32w,32w+32)
// = M-tiles w*8 .. w*8+8 (gate-interleaved, 16 rows each).
// Wave = q + 4*nh: q picks M-tile PAIR {w*8+2q, w*8+2q+1}, nh picks batch
// half. Apin[2][32] = 256 regs forced into AGPRs via inline-asm MFMA with
// "a" operands; each B-frag ds_read feeds 2 MFMAs -> per-CU LDS read 512KB.
// hbuf and LDS share the fragment-linear layout (identity fill):
// block (n,ktb) at (n*32+ktb)*1024; lane ln = h[n*16+(ln&15)][ktb*32+(ln>>4)*8+e].
// Cell lane-local: acc[mtl][n2][j] = gate j of (batch nh*32+n2*16+l15,
// feat w*32 + (2q+mtl)*4 + l4). Post-barrier roles: nh==1 publish+tag,
// nh==0 h_seq.
__global__ __launch_bounds__(512, 1) void flumen_lstm(
    const unsigned short* __restrict__ Wshuf,
    const unsigned short* __restrict__ WaugI,
    const unsigned short* __restrict__ Xhat,
    unsigned short* hbuf, int* tags, float* out)
{
  __shared__ __align__(16) char smem[140288];
  char*  h_lds = smem;                           // 128KB fragment-linear B
  float* hs    = (float*)(smem + 131072);        // [64][36] f32 staging

  float* out_hlast = out;
  float* out_hseq  = out + 65536;
  const int w    = blockIdx.x;       // 0..31
  const int tid  = threadIdx.x;
  const int lane = tid & 63;
  const int wave = tid >> 6;         // 0..7
  const int q    = wave & 3;         // M-tile pair
  const int nh   = wave >> 2;        // batch half
  const int l15  = lane & 15;
  const int l4   = lane >> 4;

  // pinned A: 2 M-tiles x 32 K-frags = 256 regs, forced to AGPR class
  bf16x8_t Apin[2][32];
#pragma unroll
  for (int mtl = 0; mtl < 2; ++mtl) {
    const char* ap = (const char*)Wshuf + (size_t)(w * 8 + q * 2 + mtl) * 32768 + lane * 16;
#pragma unroll
    for (int kt = 0; kt < 32; ++kt) {
      bf16x8_t tmp = *(const bf16x8_t*)(ap + kt * 1024);
      asm("" : "=a"(Apin[mtl][kt]) : "0"(tmp));   // VGPR -> AGPR class cast
    }
  }
  bf16x8_t wfragI[2];
#pragma unroll
  for (int mtl = 0; mtl < 2; ++mtl)
    wfragI[mtl] = *(const bf16x8_t*)((const char*)WaugI
                                     + (size_t)(w * 8 + q * 2 + mtl) * 1024 + lane * 16);

  float carr[2][2] = {{0.f, 0.f}, {0.f, 0.f}};

  for (int t = 0; t < 2048; ++t) {
    // x fragments + aug MFMAs (independent of h_t; hide under the poll)
    f32x4_t acc[2][2];
#pragma unroll
    for (int n2 = 0; n2 < 2; ++n2) {
      const int batch = nh * 32 + n2 * 16 + l15;
      bf16x8_t xf = *(const bf16x8_t*)(Xhat + ((size_t)t * 64 + batch) * 32 + l4 * 8);
#pragma unroll
      for (int mtl = 0; mtl < 2; ++mtl)
        acc[mtl][n2] = __builtin_amdgcn_mfma_f32_16x16x32_bf16(
            wfragI[mtl], xf, (f32x4_t){0.f, 0.f, 0.f, 0.f}, 0, 0, 0);
    }

    if (t > 0) {
      if (lane < 32) {   // whole wave blocks (exec-mask divergence)
        const char* tp = (const char*)tags + ((size_t)(t - 1) * 32 + lane) * 16;
        int iter = 0;
        while (true) {
          i32x4_t tv;
          asm volatile("global_load_dwordx4 %0, %1, off sc1\n\ts_waitcnt vmcnt(0)"
                       : "=v"(tv) : "v"(tp) : "memory");
          bool good = (tv[0] == t) && (tv[1] == t) && (tv[2] == t) && (tv[3] == t);
          if (__all(good) || ++iter >= (1 << 20)) break;
        }
      }
      __builtin_amdgcn_sched_barrier(0);
    }

    // identity fill: hbuf[t&1] -> h_lds (coalesced, conflict-free)
    {
      const char* src0 = (const char*)hbuf + (size_t)((t & 1) * 131072) + tid * 16;
      f32x4_t v[8];
#pragma unroll
      for (int i = 0; i < 8; ++i)
        asm volatile("global_load_dwordx4 %0, %1, off sc1"
                     : "=v"(v[i]) : "v"(src0 + i * 8192) : "memory");
      asm volatile("s_waitcnt vmcnt(0)" ::: "memory");
      __builtin_amdgcn_sched_barrier(0);
#pragma unroll
      for (int i = 0; i < 8; ++i)
        *(f32x4_t*)(h_lds + tid * 16 + i * 8192) = v[i];
#pragma unroll
      for (int i = 0; i < 8; ++i)
        asm volatile("global_load_dwordx4 %0, %1, off sc1"
                     : "=v"(v[i]) : "v"(src0 + (i + 8) * 8192) : "memory");
      asm volatile("s_waitcnt vmcnt(0)" ::: "memory");
      __builtin_amdgcn_sched_barrier(0);
#pragma unroll
      for (int i = 0; i < 8; ++i)
        *(f32x4_t*)(h_lds + tid * 16 + (i + 8) * 8192) = v[i];
    }
    __syncthreads();

    // K loop: each B-frag read feeds BOTH pinned M-tiles (asm MFMA, A in AGPR)
#pragma unroll
    for (int n2 = 0; n2 < 2; ++n2) {
      const char* bb = h_lds + (size_t)((nh * 2 + n2) * 32) * 1024 + lane * 16;
#pragma unroll
      for (int kt = 0; kt < 32; ++kt) {
        bf16x8_t bf = *(const bf16x8_t*)(bb + kt * 1024);
        asm("v_mfma_f32_16x16x32_bf16 %0, %1, %2, %0"
            : "+v"(acc[0][n2]) : "a"(Apin[0][kt]), "v"(bf));
        asm("v_mfma_f32_16x16x32_bf16 %0, %1, %2, %0"
            : "+v"(acc[1][n2]) : "a"(Apin[1][kt]), "v"(bf));
      }
    }
    // MFMA -> VALU read hazard (compiler can't see into the asm): drain
    asm volatile("s_nop 7\n\ts_nop 7\n\ts_nop 3" ::: "memory");

    // lane-local cell update: 4 cells/lane
#pragma unroll
    for (int mtl = 0; mtl < 2; ++mtl)
#pragma unroll
      for (int n2 = 0; n2 < 2; ++n2) {
        const int batch = nh * 32 + n2 * 16 + l15;
        float c = sigm(acc[mtl][n2][1]) * carr[mtl][n2]
                + sigm(acc[mtl][n2][0]) * tanh_f(acc[mtl][n2][2]);
        carr[mtl][n2] = c;
        float h = sigm(acc[mtl][n2][3]) * tanh_f(c);
        const int fl = (q * 2 + mtl) * 4 + l4;
        if (t < 2047) {
          hs[batch * 36 + fl] = h;
        } else {
          out_hlast[batch * 1024 + w * 32 + fl] = h;
        }
      }
    __syncthreads();

    if (t < 2047) {
      if (nh == 1) {
        // publish block (n=q, ktb=w): 1KB contiguous, sc1; then tag
        const int b = q * 16 + l15;
        const float* hp = hs + b * 36 + l4 * 8;
        f32x4_t u0 = *(const f32x4_t*)(hp);
        f32x4_t u1 = *(const f32x4_t*)(hp + 4);
        u64_t lo = (u64_t)f2bf(u0[0]) | ((u64_t)f2bf(u0[1]) << 16)
                 | ((u64_t)f2bf(u0[2]) << 32) | ((u64_t)f2bf(u0[3]) << 48);
        u64_t hi = (u64_t)f2bf(u1[0]) | ((u64_t)f2bf(u1[1]) << 16)
                 | ((u64_t)f2bf(u1[2]) << 32) | ((u64_t)f2bf(u1[3]) << 48);
        u64x2_t qv = {lo, hi};
        char* dst = (char*)hbuf + (size_t)(((t + 1) & 1) * 131072)
                  + (size_t)(q * 32 + w) * 1024 + lane * 16;
        asm volatile("global_store_dwordx4 %0, %1, off sc1" :: "v"(dst), "v"(qv) : "memory");
        asm volatile("s_waitcnt vmcnt(0)" ::: "memory");
        if (lane == 0) {
          int val = t + 1;
          char* tp = (char*)tags + ((size_t)t * 32 + w) * 16 + q * 4;
          asm volatile("global_store_dword %0, %1, off sc1" :: "v"(tp), "v"(val) : "memory");
        }
      } else {
        // h_seq[:, t+1, w*32..+32): full-line f32 writes, off critical path
        const int b2 = q * 16 + (lane >> 2), sg = lane & 3;
        float* hd = out_hseq + ((size_t)b2 * 2048 + (size_t)(t + 1)) * 1024 + w * 32 + sg * 8;
        *(f32x4_t*)hd       = *(const f32x4_t*)(hs + b2 * 36 + sg * 8);
        *(f32x4_t*)(hd + 4) = *(const f32x4_t*)(hs + b2 * 36 + sg * 8 + 4);
      }
    }
  }
}

// ---------------------------- launch ----------------------------

extern "C" void kernel_launch(void* const* d_in, const int* in_sizes, int n_in,
                              void* d_out, int out_size, void* d_ws, size_t ws_size,
                              hipStream_t stream) {
  const float* initial_state = (const float*)d_in[0];
  const float* rnn_input     = (const float*)d_in[1];
  const float* enc_w0        = (const float*)d_in[2];
  const float* enc_b0        = (const float*)d_in[3];
  const float* enc_w1        = (const float*)d_in[4];
  const float* enc_b1        = (const float*)d_in[5];
  const float* enc_w2        = (const float*)d_in[6];
  const float* enc_b2        = (const float*)d_in[7];
  const float* w_ih          = (const float*)d_in[8];
  const float* w_hh          = (const float*)d_in[9];
  const float* bias          = (const float*)d_in[10];

  char* ws = (char*)d_ws;
  int*            tags  = (int*)(ws + WS_TAGS);
  unsigned short* hbuf  = (unsigned short*)(ws + WS_HBUF);
  unsigned short* Wshuf = (unsigned short*)(ws + WS_WSHUF);
  unsigned short* WaugI = (unsigned short*)(ws + WS_WAUG);
  unsigned short* Xhat  = (unsigned short*)(ws + WS_XHAT);
  float*          h1    = (float*)(ws + WS_H1);
  float*          h2    = (float*)(ws + WS_H2);
  float*          out   = (float*)d_out;

  (void)hipMemsetAsync(tags, 0, 1048576, stream);
  flumen_enc1<<<64, 512, 0, stream>>>(initial_state, enc_w0, enc_b0, h1);
  flumen_enc2<<<8, 512, 0, stream>>>(h1, enc_w1, enc_b1, h2);
  flumen_enc3<<<16, 512, 0, stream>>>(h2, enc_w2, enc_b2, out, hbuf);
  flumen_wshuf<<<1024, 512, 0, stream>>>(w_hh, Wshuf);
  flumen_waugi<<<32, 512, 0, stream>>>(w_ih, bias, WaugI);
  flumen_convx<<<2048, 512, 0, stream>>>(rnn_input, Xhat);
  flumen_lstm<<<32, 512, 0, stream>>>(Wshuf, WaugI, Xhat, hbuf, tags, out);
}

// Round 10
// 18375.548 us; speedup vs baseline: 2.4420x; 2.4420x over previous
//
#include <hip/hip_runtime.h>
#include <hip/hip_bf16.h>
#include <cstdint>
#include <cstddef>

// ---------------------------------------------------------------------------
// FlumenHead: encoder MLP (32->512->512->1024) + 2048-step LSTM (D=9, F=1024)
// v9: 32 WGs x 512, K-SPLIT waves. Wave = (mtp, kh): mtp picks M-tile pair
// {w*8+2mtp, +1}, kh picks K-half (kt 16kh..16kh+15). A-pin = 2x16 frags =
// 128 regs (v5-proven size, plain intrinsics -> compiler AGPRs, no spill).
// Each wave reads only its K-half of B -> per-CU LDS read halved vs v5.
// Fragment-linear conflict-free LDS everywhere (v7b/v8-proven). Partial-sum
// exchange: kh1 writes acc into dead h-image after post-K barrier; kh0 adds,
// does all cells. v5 sync protocol (tags + whole-wave poll) unchanged.
// ---------------------------------------------------------------------------

typedef __bf16 bf16x8_t __attribute__((ext_vector_type(8)));
typedef float f32x4_t __attribute__((ext_vector_type(4)));
typedef int   i32x4_t __attribute__((ext_vector_type(4)));
typedef unsigned long long u64_t;
typedef unsigned long long u64x2_t __attribute__((ext_vector_type(2)));
typedef unsigned short u16x4_t __attribute__((ext_vector_type(4)));

// workspace layout (bytes); total ~18.6 MB
#define WS_TAGS    0          // int  tags[2048][32][4] (16B per (t,w))   1 MB
#define WS_HBUF    1048576    // u16  hbuf[2][128 blk][64 ln][8] bf16   256 KB
#define WS_WSHUF   1310720    // u16  Wshuf[256 mt][32 kt][64 ln][8]      8 MB
#define WS_WAUG    9699328    // u16  WaugI[256 mt][64 ln][8]           256 KB
#define WS_XHAT    9961472    // u16  Xhat[2048 t][64 b][32] bf16         8 MB
#define WS_H1      18350080   // f32  h1[64][512]                       128 KB
#define WS_H2      18481152   // f32  h2[64][512]                       128 KB

__device__ __forceinline__ unsigned short f2bf(float f) {
  unsigned int u = __float_as_uint(f);
  u = (u + 0x7fffu + ((u >> 16) & 1u)) >> 16;   // RNE
  return (unsigned short)u;
}
__device__ __forceinline__ float sigm(float x) { return 1.f / (1.f + __expf(-x)); }
__device__ __forceinline__ float tanh_f(float x) {
  float e = __expf(-2.f * fabsf(x));
  float r = (1.f - e) / (1.f + e);
  return copysignf(r, x);
}

// ---------------------------- encoder ----------------------------

__global__ void flumen_enc1(const float* __restrict__ x, const float* __restrict__ W,
                            const float* __restrict__ b, float* __restrict__ h1) {
  const int bb = blockIdx.x;   // batch 0..63
  const int o  = threadIdx.x;  // 0..511
  const f32x4_t* xr = (const f32x4_t*)(x + bb * 32);
  const f32x4_t* wr = (const f32x4_t*)(W + o * 32);
  float acc = b[o];
#pragma unroll
  for (int q = 0; q < 8; ++q) {
    f32x4_t xv = xr[q], wv = wr[q];
    acc += xv[0] * wv[0] + xv[1] * wv[1] + xv[2] * wv[2] + xv[3] * wv[3];
  }
  h1[bb * 512 + o] = fmaxf(acc, 0.f);
}

__global__ void flumen_enc2(const float* __restrict__ in, const float* __restrict__ W,
                            const float* __restrict__ bv, float* __restrict__ outb) {
  __shared__ float s[64 * 256];
  const int tid = threadIdx.x;
  const int ol = tid & 63, bg = tid >> 6;
  const int o = blockIdx.x * 64 + ol;
  float bias = bv[o];
  float acc[8];
#pragma unroll
  for (int q = 0; q < 8; ++q) acc[q] = bias;
  for (int p = 0; p < 2; ++p) {
    __syncthreads();
    for (int i = tid; i < 4096; i += 512) {
      int flat = i * 4;
      int bb = flat >> 8, kk = flat & 255;
      *(f32x4_t*)(s + flat) = *(const f32x4_t*)(in + bb * 512 + p * 256 + kk);
    }
    __syncthreads();
    for (int kk = 0; kk < 256; kk += 4) {
      f32x4_t wv = *(const f32x4_t*)(W + o * 512 + p * 256 + kk);
#pragma unroll
      for (int j = 0; j < 4; ++j) {
        float wj = wv[j];
#pragma unroll
        for (int q = 0; q < 8; ++q)
          acc[q] += wj * s[(bg * 8 + q) * 256 + kk + j];
      }
    }
  }
#pragma unroll
  for (int q = 0; q < 8; ++q)
    outb[(bg * 8 + q) * 512 + o] = fmaxf(acc[q], 0.f);
}

__global__ void flumen_enc3(const float* __restrict__ in, const float* __restrict__ W,
                            const float* __restrict__ bv, float* __restrict__ dout,
                            unsigned short* __restrict__ hbuf) {
  __shared__ float s[64 * 256];
  const int tid = threadIdx.x;
  const int ol = tid & 63, bg = tid >> 6;
  const int o = blockIdx.x * 64 + ol;   // 0..1023
  float bias = bv[o];
  float acc[8];
#pragma unroll
  for (int q = 0; q < 8; ++q) acc[q] = bias;
  for (int p = 0; p < 2; ++p) {
    __syncthreads();
    for (int i = tid; i < 4096; i += 512) {
      int flat = i * 4;
      int bb = flat >> 8, kk = flat & 255;
      *(f32x4_t*)(s + flat) = *(const f32x4_t*)(in + bb * 512 + p * 256 + kk);
    }
    __syncthreads();
    for (int kk = 0; kk < 256; kk += 4) {
      f32x4_t wv = *(const f32x4_t*)(W + o * 512 + p * 256 + kk);
#pragma unroll
      for (int j = 0; j < 4; ++j) {
        float wj = wv[j];
#pragma unroll
        for (int q = 0; q < 8; ++q)
          acc[q] += wj * s[(bg * 8 + q) * 256 + kk + j];
      }
    }
  }
  float* out_hseq = dout + 65536;
#pragma unroll
  for (int q = 0; q < 8; ++q) {
    int bb = bg * 8 + q;
    float v = acc[q];
    out_hseq[(size_t)bb * 2097152 + o] = v;   // h_seq[b][0][o]
    // fragment-linear hbuf[0]: block = (b>>4)*32 + (o>>5),
    // lane = ((o>>3)&3)*16 + (b&15), e = o&7
    int blk  = (bb >> 4) * 32 + (o >> 5);
    int lane = ((o >> 3) & 3) * 16 + (bb & 15);
    hbuf[blk * 512 + lane * 8 + (o & 7)] = f2bf(v);
  }
}

// ---------------------------- precompute ----------------------------

// Gate-interleaved A fragments: Wshuf[mt][kt][lane][8],
// A row r = lane&15 -> gate g = r&3, feature f = mt*4 + (r>>2);
// k = kt*32 + (lane>>4)*8 + e; src = w_hh[(g*1024+f)*1024 + k].
__global__ void flumen_wshuf(const float* __restrict__ src, unsigned short* __restrict__ dst) {
  int idx = blockIdx.x * 512 + threadIdx.x;      // 0..524287
  int lane = idx & 63, kt = (idx >> 6) & 31, mt = idx >> 11;
  int r = lane & 15;
  int g = r & 3, f = mt * 4 + (r >> 2);
  int k0 = kt * 32 + (lane >> 4) * 8;
  const float* sp = src + (size_t)(g * 1024 + f) * 1024 + k0;
  f32x4_t v0 = *(const f32x4_t*)(sp);
  f32x4_t v1 = *(const f32x4_t*)(sp + 4);
  u16x4_t o0, o1;
#pragma unroll
  for (int j = 0; j < 4; ++j) { o0[j] = f2bf(v0[j]); o1[j] = f2bf(v1[j]); }
  u16x4_t* dp = (u16x4_t*)(dst + (size_t)idx * 8);
  dp[0] = o0; dp[1] = o1;
}

// Gate-interleaved augmented fragments: WaugI[mt][lane][8], K=32:
// k<9 -> w_ih[(g*1024+f)*9+k], k==9 -> bias[g*1024+f], else 0.
__global__ void flumen_waugi(const float* __restrict__ wih, const float* __restrict__ bias,
                             unsigned short* __restrict__ dst) {
  int idx = blockIdx.x * 512 + threadIdx.x;      // 0..16383
  int lane = idx & 63, mt = idx >> 6;
  int r = lane & 15;
  int g = r & 3, f = mt * 4 + (r >> 2);
  int k0 = (lane >> 4) * 8;
  unsigned short o[8];
#pragma unroll
  for (int j = 0; j < 8; ++j) {
    int k = k0 + j;
    float v = (k < 9) ? wih[(size_t)(g * 1024 + f) * 9 + k]
                      : (k == 9 ? bias[g * 1024 + f] : 0.f);
    o[j] = f2bf(v);
  }
  u16x4_t* dp = (u16x4_t*)(dst + (size_t)idx * 8);
  dp[0] = *(u16x4_t*)&o[0];
  dp[1] = *(u16x4_t*)&o[4];
}

// Xhat[t][b][0..8]=x[b][t][:], [9]=1.0, rest 0. grid=2048.
__global__ void flumen_convx(const float* __restrict__ xin, unsigned short* __restrict__ dst) {
  int i = (blockIdx.x * 512 + threadIdx.x) * 4;   // elem index, 4 at a time
  int b = i >> 16, t = (i >> 5) & 2047, c0 = i & 31;
  u16x4_t o;
#pragma unroll
  for (int j = 0; j < 4; ++j) {
    int cc = c0 + j;
    float v = (cc < 9) ? xin[((size_t)b * 2048 + t) * 9 + cc] : (cc == 9 ? 1.f : 0.f);
    o[j] = f2bf(v);
  }
  *(u16x4_t*)(dst + ((size_t)t * 64 + b) * 32 + c0) = o;
}

// ---------------------------- persistent LSTM ----------------------------
// 32 WGs x 512 thr, 1 WG/CU (137 KB LDS). WG w owns features [32w,32w+32)
// = M-tiles w*8..w*8+8 (gate-interleaved). Wave = kh*4 + mtp:
//   mtp 0..3 -> M-tile pair {w*8+2mtp, w*8+2mtp+1}
//   kh  0..1 -> K-half, kt in [16kh, 16kh+16)
// A-pin = 2 mt x 16 kt = 128 regs (intrinsics; compiler -> AGPRs, v5-proven).
// B fragment-linear: block (n,kt) at (n*32+kt)*1024 + lane*16 (identity fill
// from hbuf, conflict-free). Each wave reads 4n x 16kt = 64 b128 -> 512KB/CU.
// Reduction: kh1 writes acc to pbuf (= dead h image) after B2; kh0 adds,
// runs all cells (acc quad = {i,f,g,o} lane-local), stages hs.
// Publish (kh1): block (mtp*32+w), 1KB contiguous + tag. h_seq: kh0.
__global__ __launch_bounds__(512, 1) void flumen_lstm(
    const unsigned short* __restrict__ Wshuf,
    const unsigned short* __restrict__ WaugI,
    const unsigned short* __restrict__ Xhat,
    unsigned short* hbuf, int* tags, float* out)
{
  __shared__ __align__(16) char smem[140288];
  char*  h_lds = smem;                           // 128KB fragment-linear B
  float* hs    = (float*)(smem + 131072);        // [64][36] f32 staging
  float* pbuf  = (float*)smem;                   // partials; aliases dead B

  float* out_hlast = out;
  float* out_hseq  = out + 65536;
  const int w    = blockIdx.x;       // 0..31
  const int tid  = threadIdx.x;
  const int lane = tid & 63;
  const int wave = tid >> 6;         // 0..7
  const int mtp  = wave & 3;         // M-tile pair
  const int kh   = wave >> 2;        // K-half
  const int l15  = lane & 15;
  const int l4   = lane >> 4;

  // pinned A: 2 M-tiles x 16 K-frags (this wave's K-half) = 128 regs
  bf16x8_t Apin[2][16];
#pragma unroll
  for (int mtl = 0; mtl < 2; ++mtl) {
    const char* ap = (const char*)Wshuf + (size_t)(w * 8 + mtp * 2 + mtl) * 32768
                   + (size_t)(kh * 16) * 1024 + lane * 16;
#pragma unroll
    for (int k16 = 0; k16 < 16; ++k16)
      Apin[mtl][k16] = *(const bf16x8_t*)(ap + k16 * 1024);
  }
  bf16x8_t wfragI[2];
#pragma unroll
  for (int mtl = 0; mtl < 2; ++mtl)
    wfragI[mtl] = *(const bf16x8_t*)((const char*)WaugI
                                     + (size_t)(w * 8 + mtp * 2 + mtl) * 1024 + lane * 16);

  float carr[2][4] = {{0.f,0.f,0.f,0.f},{0.f,0.f,0.f,0.f}};

  for (int t = 0; t < 2048; ++t) {
    f32x4_t acc[2][4];
    if (kh == 0) {
      // aug MFMAs (x-term + bias), independent of h_t: hide under the poll
#pragma unroll
      for (int n = 0; n < 4; ++n) {
        const int batch = n * 16 + l15;
        bf16x8_t xf = *(const bf16x8_t*)(Xhat + ((size_t)t * 64 + batch) * 32 + l4 * 8);
#pragma unroll
        for (int mtl = 0; mtl < 2; ++mtl)
          acc[mtl][n] = __builtin_amdgcn_mfma_f32_16x16x32_bf16(
              wfragI[mtl], xf, (f32x4_t){0.f, 0.f, 0.f, 0.f}, 0, 0, 0);
      }
    } else {
#pragma unroll
      for (int mtl = 0; mtl < 2; ++mtl)
#pragma unroll
        for (int n = 0; n < 4; ++n)
          acc[mtl][n] = (f32x4_t){0.f, 0.f, 0.f, 0.f};
    }

    if (t > 0) {
      if (lane < 32) {   // whole wave blocks (exec-mask divergence)
        const char* tp = (const char*)tags + ((size_t)(t - 1) * 32 + lane) * 16;
        int iter = 0;
        while (true) {
          i32x4_t tv;
          asm volatile("global_load_dwordx4 %0, %1, off sc1\n\ts_waitcnt vmcnt(0)"
                       : "=v"(tv) : "v"(tp) : "memory");
          bool good = (tv[0] == t) && (tv[1] == t) && (tv[2] == t) && (tv[3] == t);
          if (__all(good) || ++iter >= (1 << 20)) break;
        }
      }
      __builtin_amdgcn_sched_barrier(0);
    }

    // identity fill: hbuf[t&1] -> h_lds (coalesced, conflict-free)
    {
      const char* src0 = (const char*)hbuf + (size_t)((t & 1) * 131072) + tid * 16;
      f32x4_t v[8];
#pragma unroll
      for (int i = 0; i < 8; ++i)
        asm volatile("global_load_dwordx4 %0, %1, off sc1"
                     : "=v"(v[i]) : "v"(src0 + i * 8192) : "memory");
      asm volatile("s_waitcnt vmcnt(0)" ::: "memory");
      __builtin_amdgcn_sched_barrier(0);
#pragma unroll
      for (int i = 0; i < 8; ++i)
        *(f32x4_t*)(h_lds + tid * 16 + i * 8192) = v[i];
#pragma unroll
      for (int i = 0; i < 8; ++i)
        asm volatile("global_load_dwordx4 %0, %1, off sc1"
                     : "=v"(v[i]) : "v"(src0 + (i + 8) * 8192) : "memory");
      asm volatile("s_waitcnt vmcnt(0)" ::: "memory");
      __builtin_amdgcn_sched_barrier(0);
#pragma unroll
      for (int i = 0; i < 8; ++i)
        *(f32x4_t*)(h_lds + tid * 16 + (i + 8) * 8192) = v[i];
    }
    __syncthreads();   // B1: image ready

    // K loop: this wave's K-half of all 4 n-tiles; each B-frag feeds 2 MFMAs
#pragma unroll
    for (int n = 0; n < 4; ++n) {
      const char* bb = h_lds + (size_t)(n * 32 + kh * 16) * 1024 + lane * 16;
#pragma unroll
      for (int k16 = 0; k16 < 16; ++k16) {
        bf16x8_t bf = *(const bf16x8_t*)(bb + k16 * 1024);
        acc[0][n] = __builtin_amdgcn_mfma_f32_16x16x32_bf16(Apin[0][k16], bf, acc[0][n], 0, 0, 0);
        acc[1][n] = __builtin_amdgcn_mfma_f32_16x16x32_bf16(Apin[1][k16], bf, acc[1][n], 0, 0, 0);
      }
    }
    __syncthreads();   // B2: all K-loops done; h image dead

    if (kh == 1) {
      // write partials into dead image region (32KB), contiguous per wave
#pragma unroll
      for (int mtl = 0; mtl < 2; ++mtl)
#pragma unroll
        for (int n = 0; n < 4; ++n)
          *(f32x4_t*)(pbuf + ((size_t)((mtp * 8 + mtl * 4 + n) * 64) + lane) * 4)
              = acc[mtl][n];
    }
    __syncthreads();   // B3: partials visible

    if (kh == 0) {
      // reduce + lane-local cell (acc quad = {i,f,g,o} of one (batch,feat))
#pragma unroll
      for (int mtl = 0; mtl < 2; ++mtl)
#pragma unroll
        for (int n = 0; n < 4; ++n) {
          f32x4_t p = *(const f32x4_t*)(pbuf + ((size_t)((mtp * 8 + mtl * 4 + n) * 64) + lane) * 4);
          f32x4_t s = acc[mtl][n] + p;
          const int batch = n * 16 + l15;
          float c = sigm(s[1]) * carr[mtl][n] + sigm(s[0]) * tanh_f(s[2]);
          carr[mtl][n] = c;
          float h = sigm(s[3]) * tanh_f(c);
          const int fl = (mtp * 2 + mtl) * 4 + l4;
          if (t < 2047) {
            hs[batch * 36 + fl] = h;
          } else {
            out_hlast[batch * 1024 + w * 32 + fl] = h;
          }
        }
    }
    __syncthreads();   // B4: hs staged

    if (t < 2047) {
      if (kh == 1) {
        // publish block (n=mtp, kt=w): 1KB contiguous, sc1; then tag
        const int b = mtp * 16 + l15;
        const float* hp = hs + b * 36 + l4 * 8;
        f32x4_t u0 = *(const f32x4_t*)(hp);
        f32x4_t u1 = *(const f32x4_t*)(hp + 4);
        u64_t lo = (u64_t)f2bf(u0[0]) | ((u64_t)f2bf(u0[1]) << 16)
                 | ((u64_t)f2bf(u0[2]) << 32) | ((u64_t)f2bf(u0[3]) << 48);
        u64_t hi = (u64_t)f2bf(u1[0]) | ((u64_t)f2bf(u1[1]) << 16)
                 | ((u64_t)f2bf(u1[2]) << 32) | ((u64_t)f2bf(u1[3]) << 48);
        u64x2_t qv = {lo, hi};
        char* dst = (char*)hbuf + (size_t)(((t + 1) & 1) * 131072)
                  + (size_t)(mtp * 32 + w) * 1024 + lane * 16;
        asm volatile("global_store_dwordx4 %0, %1, off sc1" :: "v"(dst), "v"(qv) : "memory");
        asm volatile("s_waitcnt vmcnt(0)" ::: "memory");
        if (lane == 0) {
          int val = t + 1;
          char* tp = (char*)tags + ((size_t)t * 32 + w) * 16 + mtp * 4;
          asm volatile("global_store_dword %0, %1, off sc1" :: "v"(tp), "v"(val) : "memory");
        }
      } else {
        // h_seq[:, t+1, w*32..+32): full-line f32 writes, off critical path
        const int b2 = mtp * 16 + (lane >> 2), sg = lane & 3;
        float* hd = out_hseq + ((size_t)b2 * 2048 + (size_t)(t + 1)) * 1024 + w * 32 + sg * 8;
        *(f32x4_t*)hd       = *(const f32x4_t*)(hs + b2 * 36 + sg * 8);
        *(f32x4_t*)(hd + 4) = *(const f32x4_t*)(hs + b2 * 36 + sg * 8 + 4);
      }
    }
  }
}

// ---------------------------- launch ----------------------------

extern "C" void kernel_launch(void* const* d_in, const int* in_sizes, int n_in,
                              void* d_out, int out_size, void* d_ws, size_t ws_size,
                              hipStream_t stream) {
  const float* initial_state = (const float*)d_in[0];
  const float* rnn_input     = (const float*)d_in[1];
  const float* enc_w0        = (const float*)d_in[2];
  const float* enc_b0        = (const float*)d_in[3];
  const float* enc_w1        = (const float*)d_in[4];
  const float* enc_b1        = (const float*)d_in[5];
  const float* enc_w2        = (const float*)d_in[6];
  const float* enc_b2        = (const float*)d_in[7];
  const float* w_ih          = (const float*)d_in[8];
  const float* w_hh          = (const float*)d_in[9];
  const float* bias          = (const float*)d_in[10];

  char* ws = (char*)d_ws;
  int*            tags  = (int*)(ws + WS_TAGS);
  unsigned short* hbuf  = (unsigned short*)(ws + WS_HBUF);
  unsigned short* Wshuf = (unsigned short*)(ws + WS_WSHUF);
  unsigned short* WaugI = (unsigned short*)(ws + WS_WAUG);
  unsigned short* Xhat  = (unsigned short*)(ws + WS_XHAT);
  float*          h1    = (float*)(ws + WS_H1);
  float*          h2    = (float*)(ws + WS_H2);
  float*          out   = (float*)d_out;

  (void)hipMemsetAsync(tags, 0, 1048576, stream);
  flumen_enc1<<<64, 512, 0, stream>>>(initial_state, enc_w0, enc_b0, h1);
  flumen_enc2<<<8, 512, 0, stream>>>(h1, enc_w1, enc_b1, h2);
  flumen_enc3<<<16, 512, 0, stream>>>(h2, enc_w2, enc_b2, out, hbuf);
  flumen_wshuf<<<1024, 512, 0, stream>>>(w_hh, Wshuf);
  flumen_waugi<<<32, 512, 0, stream>>>(w_ih, bias, WaugI);
  flumen_convx<<<2048, 512, 0, stream>>>(rnn_input, Xhat);
  flumen_lstm<<<32, 512, 0, stream>>>(Wshuf, WaugI, Xhat, hbuf, tags, out);
}